// Round 14
// baseline (174.614 us; speedup 1.0000x reference)
//
#include <hip/hip_runtime.h>

#define NMET 200000
#define NRXN 400000
#define ESUB 800000
#define EALL 1600000

// unified streaming decomposition: 392 blocks for all count/scatter kernels
#define NBB 392
#define EBA 4096                     // met_all per block  (392*4096 >= EALL)
#define EBS 2048                     // met_sub / rxn_sub per block (392*2048 >= ESUB)

#define NBUCK_M 391                  // met buckets  (met >> 9)
#define NBUCK_R 782                  // rxn buckets  (rxn >> 9)
#define MET_MASK 0x3FFFF             // 18 bits
#define MCAP 1152                    // LDS msg tile capacity (mean bucket = 1024 recs)

// c_target = 1 + 0.5*sin(2*pi*100/1000)
#define C_TARGET 1.29389262614623664f
#define DT_C 0.01f
#define HOMEO_C 0.1f
#define LOG2_10 3.32192809488736235f

__device__ __forceinline__ float fast_tanh(float x) {
    float e = __expf(2.0f * x);
    return 1.0f - 2.0f * __builtin_amdgcn_rcpf(e + 1.0f);
}

// ---- 1. all three bucket histograms in one pass ----------------------------
__global__ __launch_bounds__(512) void k_count_all(
    const int* __restrict__ met_all, const int* __restrict__ met_sub,
    const int* __restrict__ rxn_sub,
    int* __restrict__ blockHistA, int* __restrict__ blockHistS,
    int* __restrict__ blockHistR)
{
    __shared__ int hA[NBUCK_M];
    __shared__ int hS[NBUCK_M];
    __shared__ int hR[NBUCK_R];
    int t = threadIdx.x;
    for (int b = t; b < NBUCK_R; b += 512) hR[b] = 0;
    for (int b = t; b < NBUCK_M; b += 512) { hA[b] = 0; hS[b] = 0; }
    __syncthreads();
    int baseA = blockIdx.x * EBA;
    for (int i = t; i < EBA; i += 512) {
        int e = baseA + i;
        if (e < EALL) atomicAdd(&hA[met_all[e] >> 9], 1);
    }
    int baseS = blockIdx.x * EBS;
    for (int i = t; i < EBS; i += 512) {
        int e = baseS + i;
        if (e < ESUB) {
            atomicAdd(&hS[met_sub[e] >> 9], 1);
            atomicAdd(&hR[rxn_sub[e] >> 9], 1);
        }
    }
    __syncthreads();
    for (int b = t; b < NBUCK_M; b += 512) {
        blockHistA[(size_t)b * NBB + blockIdx.x] = hA[b];
        blockHistS[(size_t)b * NBB + blockIdx.x] = hS[b];
    }
    for (int b = t; b < NBUCK_R; b += 512)
        blockHistR[(size_t)b * NBB + blockIdx.x] = hR[b];
}

// ---- 2. all per-bucket scans over the NBB block counts in one dispatch -----
__global__ __launch_bounds__(512) void k_scan_all(
    int* __restrict__ blockHistA, int* __restrict__ blockHistS,
    int* __restrict__ blockHistR,
    int* __restrict__ btotalA, int* __restrict__ btotalS,
    int* __restrict__ btotalR)
{
    __shared__ int sc[512];
    int bid = blockIdx.x;
    int* row; int* tot;
    if (bid < NBUCK_M) { row = blockHistA + (size_t)bid * NBB; tot = btotalA + bid; }
    else if (bid < 2 * NBUCK_M) { row = blockHistS + (size_t)(bid - NBUCK_M) * NBB; tot = btotalS + (bid - NBUCK_M); }
    else { row = blockHistR + (size_t)(bid - 2 * NBUCK_M) * NBB; tot = btotalR + (bid - 2 * NBUCK_M); }
    int t = threadIdx.x;
    int val = (t < NBB) ? row[t] : 0;
    sc[t] = val;
    __syncthreads();
    for (int off = 1; off < 512; off <<= 1) {
        int add = (t >= off) ? sc[t - off] : 0;
        __syncthreads();
        sc[t] += add;
        __syncthreads();
    }
    if (t < NBB) row[t] = sc[t] - val;
    if (t == 511) *tot = sc[511];
}

// ---- 3. three bucket-total scans in one dispatch ---------------------------
__global__ __launch_bounds__(1024) void k_bstart3(
    const int* __restrict__ btotalA, int* __restrict__ startA,
    const int* __restrict__ btotalS, int* __restrict__ startS,
    const int* __restrict__ btotalR, int* __restrict__ startR)
{
    __shared__ int lds[1024];
    const int* tot; int* st; int nb;
    if (blockIdx.x == 0)      { tot = btotalA; st = startA; nb = NBUCK_M; }
    else if (blockIdx.x == 1) { tot = btotalS; st = startS; nb = NBUCK_M; }
    else                      { tot = btotalR; st = startR; nb = NBUCK_R; }
    int t = threadIdx.x;
    int val = (t < nb) ? tot[t] : 0;
    lds[t] = val;
    __syncthreads();
    for (int off = 1; off < 1024; off <<= 1) {
        int add = (t >= off) ? lds[t - off] : 0;
        __syncthreads();
        lds[t] += add;
        __syncthreads();
    }
    if (t < nb) st[t] = lds[t] - val;
    if (t == 1023) st[nb] = lds[1023];
}

// ---- 4. rxn-record scatter: fat records {met|rloc, sto, conc, ext} ---------
__global__ __launch_bounds__(512) void k_rxn_scatter(
    const int* __restrict__ rxn_sub, const int* __restrict__ met_sub,
    const float* __restrict__ sto_sub, const float* __restrict__ x,
    const int* __restrict__ blockHistR, const int* __restrict__ bucketStartR,
    uint4* __restrict__ recsR)
{
    __shared__ int cnt[NBUCK_R];
    __shared__ int loff[NBUCK_R];
    __shared__ int rnk[NBUCK_R];
    __shared__ int bbase[NBUCK_R];
    __shared__ int sc[512];
    __shared__ int carry_s;
    __shared__ unsigned short perm[EBS];
    __shared__ unsigned short sbuck[EBS];
    int t = threadIdx.x;
    for (int b = t; b < NBUCK_R; b += 512) {
        cnt[b] = 0; rnk[b] = 0;
        bbase[b] = bucketStartR[b] + blockHistR[(size_t)b * NBB + blockIdx.x];
    }
    if (t == 0) carry_s = 0;
    __syncthreads();
    int base = blockIdx.x * EBS;
    int nrec = ESUB - base; if (nrec > EBS) nrec = EBS; if (nrec < 0) nrec = 0;

    for (int i = t; i < nrec; i += 512)
        atomicAdd(&cnt[rxn_sub[base + i] >> 9], 1);
    __syncthreads();
    for (int b0 = 0; b0 < NBUCK_R; b0 += 512) {
        int idx = b0 + t;
        int val = (idx < NBUCK_R) ? cnt[idx] : 0;
        sc[t] = val;
        __syncthreads();
        for (int off = 1; off < 512; off <<= 1) {
            int add = (t >= off) ? sc[t - off] : 0;
            __syncthreads();
            sc[t] += add;
            __syncthreads();
        }
        if (idx < NBUCK_R) loff[idx] = carry_s + sc[t] - val;
        __syncthreads();
        if (t == 511) carry_s += sc[511];
        __syncthreads();
    }
    for (int i = t; i < nrec; i += 512) {
        int b = rxn_sub[base + i] >> 9;
        int pos = loff[b] + atomicAdd(&rnk[b], 1);
        perm[pos] = (unsigned short)i;
        sbuck[pos] = (unsigned short)b;
    }
    __syncthreads();
    for (int j = t; j < nrec; j += 512) {
        int b = sbuck[j];
        int e = base + perm[j];
        int r = rxn_sub[e];
        int m = met_sub[e];
        uint4 rec;
        rec.x = (unsigned)(m | ((r & 511) << 18));
        rec.y = __float_as_uint(sto_sub[e]);
        rec.z = __float_as_uint(x[(size_t)m * 8 + 3]);
        rec.w = __float_as_uint(x[(size_t)m * 8 + 4]);
        recsR[bbase[b] + (j - loff[b])] = rec;
    }
}

// ---- 5. per-bucket CSR finalize: count rlocs, local scan, reorder ----------
__global__ __launch_bounds__(256) void k_csr_bucket(
    const uint4* __restrict__ recsR, const int* __restrict__ bucketStartR,
    int* __restrict__ cntG, int* __restrict__ offG, uint4* __restrict__ recsC)
{
    __shared__ int cnt[512];
    __shared__ int loff[512];
    __shared__ int pscan[256];
    __shared__ int rnk[512];
    int t = threadIdx.x;
    cnt[t] = 0; cnt[t + 256] = 0;
    rnk[t] = 0; rnk[t + 256] = 0;
    __syncthreads();

    int b = blockIdx.x;
    int s = bucketStartR[b], epos = bucketStartR[b + 1];
    for (int i = s + t; i < epos; i += 256)
        atomicAdd(&cnt[(recsR[i].x >> 18) & 511], 1);
    __syncthreads();

    int c0 = cnt[2 * t], c1 = cnt[2 * t + 1];
    int ps = c0 + c1;
    pscan[t] = ps;
    __syncthreads();
    for (int off = 1; off < 256; off <<= 1) {
        int add = (t >= off) ? pscan[t - off] : 0;
        __syncthreads();
        pscan[t] += add;
        __syncthreads();
    }
    int excl = pscan[t] - ps;
    loff[2 * t] = excl;
    loff[2 * t + 1] = excl + c0;
    __syncthreads();

    int gb = b << 9;
    for (int j = t; j < 512; j += 256) {
        cntG[gb + j] = cnt[j];
        offG[gb + j] = s + loff[j];
    }

    for (int i = s + t; i < epos; i += 256) {
        uint4 rec = recsR[i];
        int rloc = (rec.x >> 18) & 511;
        int pos = loff[rloc] + atomicAdd(&rnk[rloc], 1);
        recsC[s + pos] = rec;
    }
}

// ---- 6. FUSED per-bucket: edge MLP (2 recs/thread, b128 weights, SoA LDS) --
__global__ __launch_bounds__(512) void k_bucket2(
    const uint4* __restrict__ recsC, const int* __restrict__ bucketStartR,
    const int* __restrict__ cntG, const int* __restrict__ offG,
    const float* __restrict__ sub_w1, const float* __restrict__ sub_b1,
    const float* __restrict__ sub_w2, const float* __restrict__ sub_b2,
    const float* __restrict__ rate_w1, const float* __restrict__ rate_b1,
    const float* __restrict__ rate_w2, const float* __restrict__ rate_b2,
    const float* __restrict__ log_k, float* __restrict__ v)
{
    __shared__ __align__(16) float sW1c[256];    // [64][4] = {w1a, w1b, b1, 0}
    __shared__ __align__(16) float sW2[512];     // [64][8] (input layout)
    __shared__ __align__(16) float sR1t[512];    // [64][8] transposed rate_w1
    __shared__ float sRB1[64];
    __shared__ float sR2[64];
    __shared__ float sB2[8];
    __shared__ float sRB2;
    __shared__ float msgL[9][MCAP];              // SoA: 8 msg rows + ext row
    int t = threadIdx.x;
    sW2[t] = sub_w2[t];
    { int j = t >> 3, k = t & 7; sR1t[t] = rate_w1[k * 64 + j]; }
    if (t < 64) {
        sW1c[t * 4 + 0] = sub_w1[t];
        sW1c[t * 4 + 1] = sub_w1[64 + t];
        sW1c[t * 4 + 2] = sub_b1[t];
        sW1c[t * 4 + 3] = 0.f;
        sRB1[t] = rate_b1[t]; sR2[t] = rate_w2[t];
    }
    if (t < 8) sB2[t] = sub_b2[t];
    if (t == 8) sRB2 = rate_b2[0];
    __syncthreads();

    int b = blockIdx.x;
    int s = bucketStartR[b], epos = bucketStartR[b + 1];
    int gr = (b << 9) + t;              // this thread's reaction
    int n = cntG[gr];
    int base = offG[gr];                // absolute CSR slot
    float fn = (float)n;
    float h0 = fn * sB2[0], h1 = fn * sB2[1], h2 = fn * sB2[2], h3 = fn * sB2[3];
    float h4 = fn * sB2[4], h5 = fn * sB2[5], h6 = fn * sB2[6], h7 = fn * sB2[7];
    float exs = 0.f;

    for (int cb = s; cb < epos; cb += MCAP) {
        int ce = epos; if (ce > cb + MCAP) ce = cb + MCAP;
        // phase A: 2 records per thread share each weight load (b128s only)
        for (int i0 = cb + t; i0 < ce; i0 += 1024) {
            int i1 = i0 + 512;
            bool two = (i1 < ce);
            uint4 ra = recsC[i0];
            uint4 rb = two ? recsC[i1] : ra;
            float stA = __uint_as_float(ra.y);
            float cA  = __uint_as_float(ra.z);
            float stB = __uint_as_float(rb.y);
            float cB  = __uint_as_float(rb.z);
            float a0=0.f,a1=0.f,a2=0.f,a3=0.f,a4=0.f,a5=0.f,a6=0.f,a7=0.f;
            float b0=0.f,b1=0.f,b2=0.f,b3=0.f,b4=0.f,b5=0.f,b6=0.f,b7=0.f;
            #pragma unroll 8
            for (int j = 0; j < 64; ++j) {
                float4 wz = *(const float4*)&sW1c[j * 4];
                float za = fmaf(cA, wz.x, fmaf(stA, wz.y, wz.z));
                float zb = fmaf(cB, wz.x, fmaf(stB, wz.y, wz.z));
                float ta = fast_tanh(za);
                float tb = fast_tanh(zb);
                float4 wa = *(const float4*)&sW2[j * 8];
                float4 wb = *(const float4*)&sW2[j * 8 + 4];
                a0 = fmaf(ta, wa.x, a0); a1 = fmaf(ta, wa.y, a1);
                a2 = fmaf(ta, wa.z, a2); a3 = fmaf(ta, wa.w, a3);
                a4 = fmaf(ta, wb.x, a4); a5 = fmaf(ta, wb.y, a5);
                a6 = fmaf(ta, wb.z, a6); a7 = fmaf(ta, wb.w, a7);
                b0 = fmaf(tb, wa.x, b0); b1 = fmaf(tb, wa.y, b1);
                b2 = fmaf(tb, wa.z, b2); b3 = fmaf(tb, wa.w, b3);
                b4 = fmaf(tb, wb.x, b4); b5 = fmaf(tb, wb.y, b5);
                b6 = fmaf(tb, wb.z, b6); b7 = fmaf(tb, wb.w, b7);
            }
            int p0 = i0 - cb;
            msgL[0][p0] = a0; msgL[1][p0] = a1; msgL[2][p0] = a2; msgL[3][p0] = a3;
            msgL[4][p0] = a4; msgL[5][p0] = a5; msgL[6][p0] = a6; msgL[7][p0] = a7;
            msgL[8][p0] = __uint_as_float(ra.w);
            if (two) {
                int p1 = i1 - cb;
                msgL[0][p1] = b0; msgL[1][p1] = b1; msgL[2][p1] = b2; msgL[3][p1] = b3;
                msgL[4][p1] = b4; msgL[5][p1] = b5; msgL[6][p1] = b6; msgL[7][p1] = b7;
                msgL[8][p1] = __uint_as_float(rb.w);
            }
        }
        __syncthreads();
        // phase B: per-rxn contiguous segment sum from SoA LDS
        int lo = base;         if (lo < cb) lo = cb;
        int hi = base + n;     if (hi > ce) hi = ce;
        for (int k = lo; k < hi; ++k) {
            int p = k - cb;
            h0 += msgL[0][p]; h1 += msgL[1][p]; h2 += msgL[2][p]; h3 += msgL[3][p];
            h4 += msgL[4][p]; h5 += msgL[5][p]; h6 += msgL[6][p]; h7 += msgL[7][p];
            exs += msgL[8][p];
        }
        __syncthreads();
    }

    if (gr < NRXN) {
        float acc = sRB2;
        #pragma unroll 4
        for (int j = 0; j < 64; ++j) {
            float4 wa = *(const float4*)&sR1t[j * 8];
            float4 wb = *(const float4*)&sR1t[j * 8 + 4];
            float z = sRB1[j];
            z = fmaf(h0, wa.x, z); z = fmaf(h1, wa.y, z);
            z = fmaf(h2, wa.z, z); z = fmaf(h3, wa.w, z);
            z = fmaf(h4, wb.x, z); z = fmaf(h5, wb.y, z);
            z = fmaf(h6, wb.z, z); z = fmaf(h7, wb.w, z);
            acc = fmaf(fast_tanh(z), sR2[j], acc);
        }
        float nmax = fmaxf(fn, 1.0f);
        float ext_mean = 2.0f * exs * __builtin_amdgcn_rcpf(nmax);
        float kk = exp2f(log_k[gr] * LOG2_10);
        v[gr] = kk * ext_mean * acc;
    }
}

// ---- 7. consume bucket-scatter with LDS counting-sort staging --------------
__global__ __launch_bounds__(512) void k_cons_scatter(
    const int* __restrict__ met_sub, const int* __restrict__ rxn_sub,
    const float* __restrict__ sto_sub, const float* __restrict__ v,
    const int* __restrict__ blockHistS, const int* __restrict__ bucketStartS,
    uint2* __restrict__ recsS)
{
    __shared__ int cnt[NBUCK_M];
    __shared__ int loff[NBUCK_M];
    __shared__ int rnk[NBUCK_M];
    __shared__ int bbase[NBUCK_M];
    __shared__ int sc[512];
    __shared__ uint2 stage[EBS];
    int t = threadIdx.x;
    for (int b = t; b < NBUCK_M; b += 512) {
        cnt[b] = 0; rnk[b] = 0;
        bbase[b] = bucketStartS[b] + blockHistS[(size_t)b * NBB + blockIdx.x];
    }
    __syncthreads();
    int base = blockIdx.x * EBS;
    int nrec = ESUB - base; if (nrec > EBS) nrec = EBS; if (nrec < 0) nrec = 0;

    for (int i = t; i < nrec; i += 512)
        atomicAdd(&cnt[met_sub[base + i] >> 9], 1);
    __syncthreads();
    int cval = (t < NBUCK_M) ? cnt[t] : 0;
    sc[t] = cval;
    __syncthreads();
    for (int off = 1; off < 512; off <<= 1) {
        int add = (t >= off) ? sc[t - off] : 0;
        __syncthreads();
        sc[t] += add;
        __syncthreads();
    }
    if (t < NBUCK_M) loff[t] = sc[t] - cval;
    __syncthreads();
    for (int i = t; i < nrec; i += 512) {
        int e = base + i;
        int m = met_sub[e];
        int b = m >> 9;
        float val = sto_sub[e] * v[rxn_sub[e]] * DT_C;
        int pos = loff[b] + atomicAdd(&rnk[b], 1);
        uint2 rec;
        rec.x = (unsigned)m;
        rec.y = __float_as_uint(val);
        stage[pos] = rec;
    }
    __syncthreads();
    for (int j = t; j < nrec; j += 512) {
        uint2 rec = stage[j];
        int b = (int)(rec.x >> 9);
        recsS[bbase[b] + (j - loff[b])] = rec;
    }
}

// ---- 8. per-bucket accumulate total -> met_scale ---------------------------
__global__ __launch_bounds__(512) void k_baccum_tot(
    const uint2* __restrict__ recsS, const int* __restrict__ bucketStartS,
    const float* __restrict__ x, float* __restrict__ met_scale)
{
    __shared__ float acc[512];
    int b = blockIdx.x;
    int t = threadIdx.x;
    acc[t] = 0.f;
    __syncthreads();
    int s = bucketStartS[b], epos = bucketStartS[b + 1];
    for (int i = s + t; i < epos; i += 512) {
        uint2 rec = recsS[i];
        atomicAdd(&acc[rec.x & 511], __uint_as_float(rec.y));
    }
    __syncthreads();
    int m = (b << 9) + t;
    if (m < NMET) {
        float tot = acc[t];
        float ms = 1.0f;
        if (tot > 1e-12f) ms = fminf(x[(size_t)m * 8 + 3] / tot, 1.0f);
        met_scale[m] = ms;
    }
}

// ---- 9. per-reaction min over CSR records + v scale ------------------------
__global__ __launch_bounds__(256) void k_rscale(
    const int* __restrict__ cntG, const int* __restrict__ offG,
    const uint4* __restrict__ recsC, const float* __restrict__ met_scale,
    float* __restrict__ v)
{
    int r = blockIdx.x * 256 + threadIdx.x;
    if (r >= NRXN) return;
    int n = cntG[r];
    int base = offG[r];
    float ms = 1.0f;
    for (int i = 0; i < n; ++i)
        ms = fminf(ms, met_scale[recsC[base + i].x & MET_MASK]);
    v[r] *= ms;
}

// ---- 10. contrib bucket-scatter with LDS counting-sort staging -------------
__global__ __launch_bounds__(512) void k_bscatter(
    const int* __restrict__ met_all, const int* __restrict__ rxn_all,
    const float* __restrict__ sto_all, const float* __restrict__ v,
    const int* __restrict__ blockHistA, const int* __restrict__ bucketStartA,
    uint2* __restrict__ recsA)
{
    __shared__ int cnt[NBUCK_M];
    __shared__ int loff[NBUCK_M];
    __shared__ int rnk[NBUCK_M];
    __shared__ int bbase[NBUCK_M];
    __shared__ int sc[512];
    __shared__ uint2 stage[EBA];
    int t = threadIdx.x;
    for (int b = t; b < NBUCK_M; b += 512) {
        cnt[b] = 0; rnk[b] = 0;
        bbase[b] = bucketStartA[b] + blockHistA[(size_t)b * NBB + blockIdx.x];
    }
    __syncthreads();
    int base = blockIdx.x * EBA;
    int nrec = EALL - base; if (nrec > EBA) nrec = EBA; if (nrec < 0) nrec = 0;

    for (int i = t; i < nrec; i += 512)
        atomicAdd(&cnt[met_all[base + i] >> 9], 1);
    __syncthreads();
    int cval = (t < NBUCK_M) ? cnt[t] : 0;
    sc[t] = cval;
    __syncthreads();
    for (int off = 1; off < 512; off <<= 1) {
        int add = (t >= off) ? sc[t - off] : 0;
        __syncthreads();
        sc[t] += add;
        __syncthreads();
    }
    if (t < NBUCK_M) loff[t] = sc[t] - cval;
    __syncthreads();
    for (int i = t; i < nrec; i += 512) {
        int e = base + i;
        int m = met_all[e];
        int b = m >> 9;
        float val = sto_all[e] * v[rxn_all[e]];
        int pos = loff[b] + atomicAdd(&rnk[b], 1);
        uint2 rec;
        rec.x = (unsigned)m;
        rec.y = __float_as_uint(val);
        stage[pos] = rec;
    }
    __syncthreads();
    for (int j = t; j < nrec; j += 512) {
        uint2 rec = stage[j];
        int b = (int)(rec.x >> 9);
        recsA[bbase[b] + (j - loff[b])] = rec;
    }
}

// ---- 11. per-bucket accumulate + homeostasis epilogue ----------------------
__global__ __launch_bounds__(512) void k_baccum(
    const uint2* __restrict__ recsA, const int* __restrict__ bucketStartA,
    const float* __restrict__ x, float* __restrict__ out)
{
    __shared__ float acc[512];
    int b = blockIdx.x;
    int t = threadIdx.x;
    acc[t] = 0.f;
    __syncthreads();
    int s = bucketStartA[b], epos = bucketStartA[b + 1];
    for (int i = s + t; i < epos; i += 512) {
        uint2 rec = recsA[i];
        atomicAdd(&acc[rec.x & 511], __uint_as_float(rec.y));
    }
    __syncthreads();
    int m = (b << 9) + t;
    if (m < NMET) {
        float c = x[(size_t)m * 8 + 3];
        out[m] = acc[t] - HOMEO_C * (c - C_TARGET);
    }
}

extern "C" void kernel_launch(void* const* d_in, const int* in_sizes, int n_in,
                              void* d_out, int out_size, void* d_ws, size_t ws_size,
                              hipStream_t stream) {
    const float* x       = (const float*)d_in[0];
    const int*   met_sub = (const int*)  d_in[1];
    const int*   rxn_sub = (const int*)  d_in[2];
    const float* sto_sub = (const float*)d_in[3];
    const int*   met_all = (const int*)  d_in[4];
    const int*   rxn_all = (const int*)  d_in[5];
    const float* sto_all = (const float*)d_in[6];
    const float* sub_w1  = (const float*)d_in[7];
    const float* sub_b1  = (const float*)d_in[8];
    const float* sub_w2  = (const float*)d_in[9];
    const float* sub_b2  = (const float*)d_in[10];
    const float* rate_w1 = (const float*)d_in[11];
    const float* rate_b1 = (const float*)d_in[12];
    const float* rate_w2 = (const float*)d_in[13];
    const float* rate_b2 = (const float*)d_in[14];
    const float* log_k   = (const float*)d_in[15];

    char* ws = (char*)d_ws;
    uint4* recsR = (uint4*)ws;                                  // ESUB (16B)
    uint4* recsC = recsR + ESUB;                                // ESUB (16B)
    uint2* recsS = (uint2*)(recsC + ESUB);                      // ESUB
    uint2* recsA = recsS + ESUB;                                // EALL
    float* v     = (float*)(recsA + EALL);                      // NRXN
    float* met_scale = v + NRXN;                                // NMET
    int* cntG = (int*)(met_scale + NMET);                       // NBUCK_R*512
    int* offG = cntG + (size_t)NBUCK_R * 512;                   // NBUCK_R*512
    int* blockHistA = offG + (size_t)NBUCK_R * 512;             // NBUCK_M*NBB
    int* blockHistS = blockHistA + (size_t)NBUCK_M * NBB;       // NBUCK_M*NBB
    int* blockHistR = blockHistS + (size_t)NBUCK_M * NBB;       // NBUCK_R*NBB
    int* btotalA = blockHistR + (size_t)NBUCK_R * NBB;          // NBUCK_M
    int* bucketStartA = btotalA + NBUCK_M;                      // NBUCK_M+1
    int* btotalS = bucketStartA + NBUCK_M + 1;                  // NBUCK_M
    int* bucketStartS = btotalS + NBUCK_M;                      // NBUCK_M+1
    int* btotalR = bucketStartS + NBUCK_M + 1;                  // NBUCK_R
    int* bucketStartR = btotalR + NBUCK_R;                      // NBUCK_R+1
    float* out = (float*)d_out;

    dim3 blk256(256);
    dim3 blk512(512);
    k_count_all<<<dim3(NBB), blk512, 0, stream>>>(
        met_all, met_sub, rxn_sub, blockHistA, blockHistS, blockHistR);
    k_scan_all<<<dim3(2 * NBUCK_M + NBUCK_R), blk512, 0, stream>>>(
        blockHistA, blockHistS, blockHistR, btotalA, btotalS, btotalR);
    k_bstart3<<<dim3(3), dim3(1024), 0, stream>>>(
        btotalA, bucketStartA, btotalS, bucketStartS, btotalR, bucketStartR);
    k_rxn_scatter<<<dim3(NBB), blk512, 0, stream>>>(
        rxn_sub, met_sub, sto_sub, x, blockHistR, bucketStartR, recsR);
    k_csr_bucket<<<dim3(NBUCK_R), blk256, 0, stream>>>(
        recsR, bucketStartR, cntG, offG, recsC);
    k_bucket2<<<dim3(NBUCK_R), blk512, 0, stream>>>(
        recsC, bucketStartR, cntG, offG,
        sub_w1, sub_b1, sub_w2, sub_b2,
        rate_w1, rate_b1, rate_w2, rate_b2, log_k, v);
    k_cons_scatter<<<dim3(NBB), blk512, 0, stream>>>(
        met_sub, rxn_sub, sto_sub, v, blockHistS, bucketStartS, recsS);
    k_baccum_tot<<<dim3(NBUCK_M), blk512, 0, stream>>>(
        recsS, bucketStartS, x, met_scale);
    k_rscale<<<dim3((NRXN + 255) / 256), blk256, 0, stream>>>(
        cntG, offG, recsC, met_scale, v);
    k_bscatter<<<dim3(NBB), blk512, 0, stream>>>(
        met_all, rxn_all, sto_all, v, blockHistA, bucketStartA, recsA);
    k_baccum<<<dim3(NBUCK_M), blk512, 0, stream>>>(recsA, bucketStartA, x, out);
}

// Round 15
// 166.658 us; speedup vs baseline: 1.0477x; 1.0477x over previous
//
#include <hip/hip_runtime.h>

#define NMET 200000
#define NRXN 400000
#define ESUB 800000
#define EALL 1600000

// unified streaming decomposition: 196 blocks for all count/scatter kernels
#define NBB 196
#define EBA 8192                     // met_all per block  (196*8192 >= EALL)
#define EBS 4096                     // met_sub / rxn_sub per block (196*4096 >= ESUB)

#define NBUCK_M 391                  // met buckets  (met >> 9)
#define NBUCK_R 782                  // rxn buckets  (rxn >> 9)
#define MET_MASK 0x3FFFF             // 18 bits
#define MCAP 1280                    // LDS msg tile capacity (mean bucket = 1024 recs)

// c_target = 1 + 0.5*sin(2*pi*100/1000)
#define C_TARGET 1.29389262614623664f
#define DT_C 0.01f
#define HOMEO_C 0.1f
#define LOG2_10 3.32192809488736235f

__device__ __forceinline__ float fast_tanh(float x) {
    float e = __expf(2.0f * x);
    return 1.0f - 2.0f * __builtin_amdgcn_rcpf(e + 1.0f);
}

// ---- 0. compact x[:,3],x[:,4] -> xc (1.6 MB, L2/L3-resident gather target) -
__global__ __launch_bounds__(512) void k_xc(
    const float* __restrict__ x, float2* __restrict__ xc)
{
    int m = blockIdx.x * 512 + threadIdx.x;
    if (m >= NMET) return;
    float2 cx;
    cx.x = x[(size_t)m * 8 + 3];
    cx.y = x[(size_t)m * 8 + 4];
    xc[m] = cx;
}

// ---- 1. all three bucket histograms in one pass ----------------------------
__global__ __launch_bounds__(512) void k_count_all(
    const int* __restrict__ met_all, const int* __restrict__ met_sub,
    const int* __restrict__ rxn_sub,
    int* __restrict__ blockHistA, int* __restrict__ blockHistS,
    int* __restrict__ blockHistR)
{
    __shared__ int hA[NBUCK_M];
    __shared__ int hS[NBUCK_M];
    __shared__ int hR[NBUCK_R];
    int t = threadIdx.x;
    for (int b = t; b < NBUCK_R; b += 512) hR[b] = 0;
    for (int b = t; b < NBUCK_M; b += 512) { hA[b] = 0; hS[b] = 0; }
    __syncthreads();
    int baseA = blockIdx.x * EBA;
    for (int i = t; i < EBA; i += 512) {
        int e = baseA + i;
        if (e < EALL) atomicAdd(&hA[met_all[e] >> 9], 1);
    }
    int baseS = blockIdx.x * EBS;
    for (int i = t; i < EBS; i += 512) {
        int e = baseS + i;
        if (e < ESUB) {
            atomicAdd(&hS[met_sub[e] >> 9], 1);
            atomicAdd(&hR[rxn_sub[e] >> 9], 1);
        }
    }
    __syncthreads();
    for (int b = t; b < NBUCK_M; b += 512) {
        blockHistA[(size_t)b * NBB + blockIdx.x] = hA[b];
        blockHistS[(size_t)b * NBB + blockIdx.x] = hS[b];
    }
    for (int b = t; b < NBUCK_R; b += 512)
        blockHistR[(size_t)b * NBB + blockIdx.x] = hR[b];
}

// ---- 2. all per-bucket scans over the NBB block counts in one dispatch -----
__global__ __launch_bounds__(256) void k_scan_all(
    int* __restrict__ blockHistA, int* __restrict__ blockHistS,
    int* __restrict__ blockHistR,
    int* __restrict__ btotalA, int* __restrict__ btotalS,
    int* __restrict__ btotalR)
{
    __shared__ int sc[256];
    int bid = blockIdx.x;
    int* row; int* tot;
    if (bid < NBUCK_M) { row = blockHistA + (size_t)bid * NBB; tot = btotalA + bid; }
    else if (bid < 2 * NBUCK_M) { row = blockHistS + (size_t)(bid - NBUCK_M) * NBB; tot = btotalS + (bid - NBUCK_M); }
    else { row = blockHistR + (size_t)(bid - 2 * NBUCK_M) * NBB; tot = btotalR + (bid - 2 * NBUCK_M); }
    int t = threadIdx.x;
    int val = (t < NBB) ? row[t] : 0;
    sc[t] = val;
    __syncthreads();
    for (int off = 1; off < 256; off <<= 1) {
        int add = (t >= off) ? sc[t - off] : 0;
        __syncthreads();
        sc[t] += add;
        __syncthreads();
    }
    if (t < NBB) row[t] = sc[t] - val;
    if (t == 255) *tot = sc[255];
}

// ---- 3. three bucket-total scans in one dispatch ---------------------------
__global__ __launch_bounds__(1024) void k_bstart3(
    const int* __restrict__ btotalA, int* __restrict__ startA,
    const int* __restrict__ btotalS, int* __restrict__ startS,
    const int* __restrict__ btotalR, int* __restrict__ startR)
{
    __shared__ int lds[1024];
    const int* tot; int* st; int nb;
    if (blockIdx.x == 0)      { tot = btotalA; st = startA; nb = NBUCK_M; }
    else if (blockIdx.x == 1) { tot = btotalS; st = startS; nb = NBUCK_M; }
    else                      { tot = btotalR; st = startR; nb = NBUCK_R; }
    int t = threadIdx.x;
    int val = (t < nb) ? tot[t] : 0;
    lds[t] = val;
    __syncthreads();
    for (int off = 1; off < 1024; off <<= 1) {
        int add = (t >= off) ? lds[t - off] : 0;
        __syncthreads();
        lds[t] += add;
        __syncthreads();
    }
    if (t < nb) st[t] = lds[t] - val;
    if (t == 1023) st[nb] = lds[1023];
}

// ---- 4. rxn-record scatter with LDS counting-sort staging ------------------
__global__ __launch_bounds__(512) void k_rxn_scatter(
    const int* __restrict__ rxn_sub, const int* __restrict__ met_sub,
    const float* __restrict__ sto_sub,
    const int* __restrict__ blockHistR, const int* __restrict__ bucketStartR,
    uint2* __restrict__ recsR)
{
    __shared__ int cnt[NBUCK_R];
    __shared__ int loff[NBUCK_R];
    __shared__ int rnk[NBUCK_R];
    __shared__ int bbase[NBUCK_R];
    __shared__ unsigned short sbuck[EBS];
    __shared__ uint2 stage[EBS];
    __shared__ int sc[512];
    __shared__ int carry_s;
    int t = threadIdx.x;
    for (int b = t; b < NBUCK_R; b += 512) {
        cnt[b] = 0; rnk[b] = 0;
        bbase[b] = bucketStartR[b] + blockHistR[(size_t)b * NBB + blockIdx.x];
    }
    if (t == 0) carry_s = 0;
    __syncthreads();
    int base = blockIdx.x * EBS;
    int nrec = ESUB - base; if (nrec > EBS) nrec = EBS; if (nrec < 0) nrec = 0;

    for (int i = t; i < nrec; i += 512)
        atomicAdd(&cnt[rxn_sub[base + i] >> 9], 1);
    __syncthreads();
    // 782-wide exclusive scan with 512 threads (2 passes + carry)
    for (int b0 = 0; b0 < NBUCK_R; b0 += 512) {
        int idx = b0 + t;
        int val = (idx < NBUCK_R) ? cnt[idx] : 0;
        sc[t] = val;
        __syncthreads();
        for (int off = 1; off < 512; off <<= 1) {
            int add = (t >= off) ? sc[t - off] : 0;
            __syncthreads();
            sc[t] += add;
            __syncthreads();
        }
        if (idx < NBUCK_R) loff[idx] = carry_s + sc[t] - val;
        __syncthreads();
        if (t == 511) carry_s += sc[511];
        __syncthreads();
    }
    for (int i = t; i < nrec; i += 512) {
        int e = base + i;
        int r = rxn_sub[e];
        int b = r >> 9;
        int pos = loff[b] + atomicAdd(&rnk[b], 1);
        uint2 rec;
        rec.x = (unsigned)(met_sub[e] | ((r & 511) << 18));
        rec.y = __float_as_uint(sto_sub[e]);
        stage[pos] = rec;
        sbuck[pos] = (unsigned short)b;
    }
    __syncthreads();
    for (int j = t; j < nrec; j += 512) {
        int b = sbuck[j];
        recsR[bbase[b] + (j - loff[b])] = stage[j];
    }
}

// ---- 5. per-bucket CSR finalize: count rlocs, local scan, reorder ----------
__global__ __launch_bounds__(256) void k_csr_bucket(
    const uint2* __restrict__ recsR, const int* __restrict__ bucketStartR,
    int* __restrict__ cntG, int* __restrict__ offG, uint2* __restrict__ recsC)
{
    __shared__ int cnt[512];
    __shared__ int loff[512];
    __shared__ int pscan[256];
    __shared__ int rnk[512];
    int t = threadIdx.x;
    cnt[t] = 0; cnt[t + 256] = 0;
    rnk[t] = 0; rnk[t + 256] = 0;
    __syncthreads();

    int b = blockIdx.x;
    int s = bucketStartR[b], epos = bucketStartR[b + 1];
    for (int i = s + t; i < epos; i += 256)
        atomicAdd(&cnt[(recsR[i].x >> 18) & 511], 1);
    __syncthreads();

    int c0 = cnt[2 * t], c1 = cnt[2 * t + 1];
    int ps = c0 + c1;
    pscan[t] = ps;
    __syncthreads();
    for (int off = 1; off < 256; off <<= 1) {
        int add = (t >= off) ? pscan[t - off] : 0;
        __syncthreads();
        pscan[t] += add;
        __syncthreads();
    }
    int excl = pscan[t] - ps;
    loff[2 * t] = excl;
    loff[2 * t + 1] = excl + c0;
    __syncthreads();

    int gb = b << 9;
    for (int j = t; j < 512; j += 256) {
        cntG[gb + j] = cnt[j];
        offG[gb + j] = s + loff[j];
    }

    for (int i = s + t; i < epos; i += 256) {
        uint2 rec = recsR[i];
        int rloc = (rec.x >> 18) & 511;
        int pos = loff[rloc] + atomicAdd(&rnk[rloc], 1);
        recsC[s + pos] = rec;
    }
}

// ---- 6. FUSED per-bucket: edge MLP -> LDS msg tile -> segment sum -> rate MLP
__global__ __launch_bounds__(512) void k_bucket2(
    const uint2* __restrict__ recsC, const int* __restrict__ bucketStartR,
    const int* __restrict__ cntG, const int* __restrict__ offG,
    const float2* __restrict__ xc,
    const float* __restrict__ sub_w1, const float* __restrict__ sub_b1,
    const float* __restrict__ sub_w2, const float* __restrict__ sub_b2,
    const float* __restrict__ rate_w1, const float* __restrict__ rate_b1,
    const float* __restrict__ rate_w2, const float* __restrict__ rate_b2,
    const float* __restrict__ log_k, float* __restrict__ v)
{
    __shared__ float sW1[128];
    __shared__ float sB1[64];
    __shared__ __align__(16) float sW2[512];
    __shared__ __align__(16) float sR1t[512];    // [64][8] transposed rate_w1
    __shared__ float sRB1[64];
    __shared__ float sR2[64];
    __shared__ float sB2[8];
    __shared__ float sRB2;
    __shared__ float msgL[MCAP][9];     // 8 msg + ext per record
    int t = threadIdx.x;
    sW2[t] = sub_w2[t];
    { int j = t >> 3, k = t & 7; sR1t[t] = rate_w1[k * 64 + j]; }
    if (t < 128) sW1[t] = sub_w1[t];
    if (t < 64) { sB1[t] = sub_b1[t]; sRB1[t] = rate_b1[t]; sR2[t] = rate_w2[t]; }
    if (t < 8) sB2[t] = sub_b2[t];
    if (t == 8) sRB2 = rate_b2[0];
    __syncthreads();

    int b = blockIdx.x;
    int s = bucketStartR[b], epos = bucketStartR[b + 1];
    int gr = (b << 9) + t;              // this thread's reaction
    int n = cntG[gr];
    int base = offG[gr];                // absolute CSR slot
    float fn = (float)n;
    float h0 = fn * sB2[0], h1 = fn * sB2[1], h2 = fn * sB2[2], h3 = fn * sB2[3];
    float h4 = fn * sB2[4], h5 = fn * sB2[5], h6 = fn * sB2[6], h7 = fn * sB2[7];
    float exs = 0.f;

    for (int cb = s; cb < epos; cb += MCAP) {
        int ce = epos; if (ce > cb + MCAP) ce = cb + MCAP;
        // phase A: edge-parallel MLP; gather hits L2-resident xc (1.6 MB)
        for (int i = cb + t; i < ce; i += 512) {
            uint2 rec = recsC[i];
            int m = rec.x & MET_MASK;
            float st = __uint_as_float(rec.y);
            float2 cx = xc[m];
            float c  = cx.x;
            float ex = cx.y;
            float m0 = 0.f, m1 = 0.f, m2 = 0.f, m3 = 0.f;
            float m4 = 0.f, m5 = 0.f, m6 = 0.f, m7 = 0.f;
            #pragma unroll 8
            for (int j = 0; j < 64; ++j) {
                float z = fmaf(c, sW1[j], fmaf(st, sW1[64 + j], sB1[j]));
                float th = fast_tanh(z);
                float4 wa = *(const float4*)&sW2[j * 8];
                float4 wb = *(const float4*)&sW2[j * 8 + 4];
                m0 = fmaf(th, wa.x, m0); m1 = fmaf(th, wa.y, m1);
                m2 = fmaf(th, wa.z, m2); m3 = fmaf(th, wa.w, m3);
                m4 = fmaf(th, wb.x, m4); m5 = fmaf(th, wb.y, m5);
                m6 = fmaf(th, wb.z, m6); m7 = fmaf(th, wb.w, m7);
            }
            float* row = msgL[i - cb];
            row[0] = m0; row[1] = m1; row[2] = m2; row[3] = m3;
            row[4] = m4; row[5] = m5; row[6] = m6; row[7] = m7;
            row[8] = ex;
        }
        __syncthreads();
        // phase B: per-rxn contiguous segment sum from LDS
        int lo = base;         if (lo < cb) lo = cb;
        int hi = base + n;     if (hi > ce) hi = ce;
        for (int k = lo; k < hi; ++k) {
            float* row = msgL[k - cb];
            h0 += row[0]; h1 += row[1]; h2 += row[2]; h3 += row[3];
            h4 += row[4]; h5 += row[5]; h6 += row[6]; h7 += row[7];
            exs += row[8];
        }
        __syncthreads();
    }

    if (gr < NRXN) {
        float acc = sRB2;
        #pragma unroll 4
        for (int j = 0; j < 64; ++j) {
            float4 wa = *(const float4*)&sR1t[j * 8];
            float4 wb = *(const float4*)&sR1t[j * 8 + 4];
            float z = sRB1[j];
            z = fmaf(h0, wa.x, z); z = fmaf(h1, wa.y, z);
            z = fmaf(h2, wa.z, z); z = fmaf(h3, wa.w, z);
            z = fmaf(h4, wb.x, z); z = fmaf(h5, wb.y, z);
            z = fmaf(h6, wb.z, z); z = fmaf(h7, wb.w, z);
            acc = fmaf(fast_tanh(z), sR2[j], acc);
        }
        float nmax = fmaxf(fn, 1.0f);
        float ext_mean = 2.0f * exs * __builtin_amdgcn_rcpf(nmax);
        float kk = exp2f(log_k[gr] * LOG2_10);
        v[gr] = kk * ext_mean * acc;
    }
}

// ---- 7. consume bucket-scatter with LDS counting-sort staging --------------
__global__ __launch_bounds__(512) void k_cons_scatter(
    const int* __restrict__ met_sub, const int* __restrict__ rxn_sub,
    const float* __restrict__ sto_sub, const float* __restrict__ v,
    const int* __restrict__ blockHistS, const int* __restrict__ bucketStartS,
    uint2* __restrict__ recsS)
{
    __shared__ int cnt[NBUCK_M];
    __shared__ int loff[NBUCK_M];
    __shared__ int rnk[NBUCK_M];
    __shared__ int bbase[NBUCK_M];
    __shared__ int sc[512];
    __shared__ uint2 stage[EBS];
    int t = threadIdx.x;
    for (int b = t; b < NBUCK_M; b += 512) {
        cnt[b] = 0; rnk[b] = 0;
        bbase[b] = bucketStartS[b] + blockHistS[(size_t)b * NBB + blockIdx.x];
    }
    __syncthreads();
    int base = blockIdx.x * EBS;
    int nrec = ESUB - base; if (nrec > EBS) nrec = EBS; if (nrec < 0) nrec = 0;

    for (int i = t; i < nrec; i += 512)
        atomicAdd(&cnt[met_sub[base + i] >> 9], 1);
    __syncthreads();
    int cval = (t < NBUCK_M) ? cnt[t] : 0;
    sc[t] = cval;
    __syncthreads();
    for (int off = 1; off < 512; off <<= 1) {
        int add = (t >= off) ? sc[t - off] : 0;
        __syncthreads();
        sc[t] += add;
        __syncthreads();
    }
    if (t < NBUCK_M) loff[t] = sc[t] - cval;
    __syncthreads();
    for (int i = t; i < nrec; i += 512) {
        int e = base + i;
        int m = met_sub[e];
        int b = m >> 9;
        float val = sto_sub[e] * v[rxn_sub[e]] * DT_C;
        int pos = loff[b] + atomicAdd(&rnk[b], 1);
        uint2 rec;
        rec.x = (unsigned)m;
        rec.y = __float_as_uint(val);
        stage[pos] = rec;
    }
    __syncthreads();
    for (int j = t; j < nrec; j += 512) {
        uint2 rec = stage[j];
        int b = (int)(rec.x >> 9);
        recsS[bbase[b] + (j - loff[b])] = rec;
    }
}

// ---- 8. per-bucket accumulate total -> met_scale ---------------------------
__global__ __launch_bounds__(512) void k_baccum_tot(
    const uint2* __restrict__ recsS, const int* __restrict__ bucketStartS,
    const float* __restrict__ x, float* __restrict__ met_scale)
{
    __shared__ float acc[512];
    int b = blockIdx.x;
    int t = threadIdx.x;
    acc[t] = 0.f;
    __syncthreads();
    int s = bucketStartS[b], epos = bucketStartS[b + 1];
    for (int i = s + t; i < epos; i += 512) {
        uint2 rec = recsS[i];
        atomicAdd(&acc[rec.x & 511], __uint_as_float(rec.y));
    }
    __syncthreads();
    int m = (b << 9) + t;
    if (m < NMET) {
        float tot = acc[t];
        float ms = 1.0f;
        if (tot > 1e-12f) ms = fminf(x[(size_t)m * 8 + 3] / tot, 1.0f);
        met_scale[m] = ms;
    }
}

// ---- 9. per-reaction min over CSR records + v scale ------------------------
__global__ __launch_bounds__(256) void k_rscale(
    const int* __restrict__ cntG, const int* __restrict__ offG,
    const uint2* __restrict__ recsC, const float* __restrict__ met_scale,
    float* __restrict__ v)
{
    int r = blockIdx.x * 256 + threadIdx.x;
    if (r >= NRXN) return;
    int n = cntG[r];
    int base = offG[r];
    float ms = 1.0f;
    for (int i = 0; i < n; ++i)
        ms = fminf(ms, met_scale[recsC[base + i].x & MET_MASK]);
    v[r] *= ms;
}

// ---- 10. contrib bucket-scatter with LDS counting-sort staging -------------
__global__ __launch_bounds__(512) void k_bscatter(
    const int* __restrict__ met_all, const int* __restrict__ rxn_all,
    const float* __restrict__ sto_all, const float* __restrict__ v,
    const int* __restrict__ blockHistA, const int* __restrict__ bucketStartA,
    uint2* __restrict__ recsA)
{
    __shared__ int cnt[NBUCK_M];
    __shared__ int loff[NBUCK_M];
    __shared__ int rnk[NBUCK_M];
    __shared__ int bbase[NBUCK_M];
    __shared__ int sc[512];
    __shared__ uint2 stage[EBA];
    int t = threadIdx.x;
    for (int b = t; b < NBUCK_M; b += 512) {
        cnt[b] = 0; rnk[b] = 0;
        bbase[b] = bucketStartA[b] + blockHistA[(size_t)b * NBB + blockIdx.x];
    }
    __syncthreads();
    int base = blockIdx.x * EBA;
    int nrec = EALL - base; if (nrec > EBA) nrec = EBA; if (nrec < 0) nrec = 0;

    for (int i = t; i < nrec; i += 512)
        atomicAdd(&cnt[met_all[base + i] >> 9], 1);
    __syncthreads();
    int cval = (t < NBUCK_M) ? cnt[t] : 0;
    sc[t] = cval;
    __syncthreads();
    for (int off = 1; off < 512; off <<= 1) {
        int add = (t >= off) ? sc[t - off] : 0;
        __syncthreads();
        sc[t] += add;
        __syncthreads();
    }
    if (t < NBUCK_M) loff[t] = sc[t] - cval;
    __syncthreads();
    for (int i = t; i < nrec; i += 512) {
        int e = base + i;
        int m = met_all[e];
        int b = m >> 9;
        float val = sto_all[e] * v[rxn_all[e]];
        int pos = loff[b] + atomicAdd(&rnk[b], 1);
        uint2 rec;
        rec.x = (unsigned)m;
        rec.y = __float_as_uint(val);
        stage[pos] = rec;
    }
    __syncthreads();
    for (int j = t; j < nrec; j += 512) {
        uint2 rec = stage[j];
        int b = (int)(rec.x >> 9);
        recsA[bbase[b] + (j - loff[b])] = rec;
    }
}

// ---- 11. per-bucket accumulate + homeostasis epilogue ----------------------
__global__ __launch_bounds__(512) void k_baccum(
    const uint2* __restrict__ recsA, const int* __restrict__ bucketStartA,
    const float* __restrict__ x, float* __restrict__ out)
{
    __shared__ float acc[512];
    int b = blockIdx.x;
    int t = threadIdx.x;
    acc[t] = 0.f;
    __syncthreads();
    int s = bucketStartA[b], epos = bucketStartA[b + 1];
    for (int i = s + t; i < epos; i += 512) {
        uint2 rec = recsA[i];
        atomicAdd(&acc[rec.x & 511], __uint_as_float(rec.y));
    }
    __syncthreads();
    int m = (b << 9) + t;
    if (m < NMET) {
        float c = x[(size_t)m * 8 + 3];
        out[m] = acc[t] - HOMEO_C * (c - C_TARGET);
    }
}

extern "C" void kernel_launch(void* const* d_in, const int* in_sizes, int n_in,
                              void* d_out, int out_size, void* d_ws, size_t ws_size,
                              hipStream_t stream) {
    const float* x       = (const float*)d_in[0];
    const int*   met_sub = (const int*)  d_in[1];
    const int*   rxn_sub = (const int*)  d_in[2];
    const float* sto_sub = (const float*)d_in[3];
    const int*   met_all = (const int*)  d_in[4];
    const int*   rxn_all = (const int*)  d_in[5];
    const float* sto_all = (const float*)d_in[6];
    const float* sub_w1  = (const float*)d_in[7];
    const float* sub_b1  = (const float*)d_in[8];
    const float* sub_w2  = (const float*)d_in[9];
    const float* sub_b2  = (const float*)d_in[10];
    const float* rate_w1 = (const float*)d_in[11];
    const float* rate_b1 = (const float*)d_in[12];
    const float* rate_w2 = (const float*)d_in[13];
    const float* rate_b2 = (const float*)d_in[14];
    const float* log_k   = (const float*)d_in[15];

    char* ws = (char*)d_ws;
    uint2*  recsR = (uint2*)ws;                                 // ESUB
    uint2*  recsC = recsR + ESUB;                               // ESUB
    uint2*  recsS = recsC + ESUB;                               // ESUB
    uint2*  recsA = recsS + ESUB;                               // EALL
    float2* xc    = (float2*)(recsA + EALL);                    // NMET
    float*  v     = (float*)(xc + NMET);                        // NRXN
    float*  met_scale = v + NRXN;                               // NMET
    int* cntG = (int*)(met_scale + NMET);                       // NBUCK_R*512
    int* offG = cntG + (size_t)NBUCK_R * 512;                   // NBUCK_R*512
    int* blockHistA = offG + (size_t)NBUCK_R * 512;             // NBUCK_M*NBB
    int* blockHistS = blockHistA + (size_t)NBUCK_M * NBB;       // NBUCK_M*NBB
    int* blockHistR = blockHistS + (size_t)NBUCK_M * NBB;       // NBUCK_R*NBB
    int* btotalA = blockHistR + (size_t)NBUCK_R * NBB;          // NBUCK_M
    int* bucketStartA = btotalA + NBUCK_M;                      // NBUCK_M+1
    int* btotalS = bucketStartA + NBUCK_M + 1;                  // NBUCK_M
    int* bucketStartS = btotalS + NBUCK_M;                      // NBUCK_M+1
    int* btotalR = bucketStartS + NBUCK_M + 1;                  // NBUCK_R
    int* bucketStartR = btotalR + NBUCK_R;                      // NBUCK_R+1
    float* out = (float*)d_out;

    dim3 blk256(256);
    dim3 blk512(512);
    k_xc<<<dim3((NMET + 511) / 512), blk512, 0, stream>>>(x, xc);
    k_count_all<<<dim3(NBB), blk512, 0, stream>>>(
        met_all, met_sub, rxn_sub, blockHistA, blockHistS, blockHistR);
    k_scan_all<<<dim3(2 * NBUCK_M + NBUCK_R), blk256, 0, stream>>>(
        blockHistA, blockHistS, blockHistR, btotalA, btotalS, btotalR);
    k_bstart3<<<dim3(3), dim3(1024), 0, stream>>>(
        btotalA, bucketStartA, btotalS, bucketStartS, btotalR, bucketStartR);
    k_rxn_scatter<<<dim3(NBB), blk512, 0, stream>>>(
        rxn_sub, met_sub, sto_sub, blockHistR, bucketStartR, recsR);
    k_csr_bucket<<<dim3(NBUCK_R), blk256, 0, stream>>>(
        recsR, bucketStartR, cntG, offG, recsC);
    k_bucket2<<<dim3(NBUCK_R), blk512, 0, stream>>>(
        recsC, bucketStartR, cntG, offG, xc,
        sub_w1, sub_b1, sub_w2, sub_b2,
        rate_w1, rate_b1, rate_w2, rate_b2, log_k, v);
    k_cons_scatter<<<dim3(NBB), blk512, 0, stream>>>(
        met_sub, rxn_sub, sto_sub, v, blockHistS, bucketStartS, recsS);
    k_baccum_tot<<<dim3(NBUCK_M), blk512, 0, stream>>>(
        recsS, bucketStartS, x, met_scale);
    k_rscale<<<dim3((NRXN + 255) / 256), blk256, 0, stream>>>(
        cntG, offG, recsC, met_scale, v);
    k_bscatter<<<dim3(NBB), blk512, 0, stream>>>(
        met_all, rxn_all, sto_all, v, blockHistA, bucketStartA, recsA);
    k_baccum<<<dim3(NBUCK_M), blk512, 0, stream>>>(recsA, bucketStartA, x, out);
}